// Round 7
// baseline (317.524 us; speedup 1.0000x reference)
//
#include <hip/hip_runtime.h>
#include <math.h>

#define LEN   2048
#define EDIM  512
#define NB    16
#define NH    8
#define HD    64
#define TOPK  7
#define NXCD  8

__device__ inline float2 cmul(float2 a, float2 b) {
    return make_float2(a.x * b.x - a.y * b.y, a.x * b.y + a.y * b.x);
}
__device__ inline float2 cadd(float2 a, float2 b) { return make_float2(a.x + b.x, a.y + b.y); }
__device__ inline float2 csub(float2 a, float2 b) { return make_float2(a.x - b.x, a.y - b.y); }
// XOR swizzle: arrays stay exactly 2048 float2 (A+Bs = 32 KB -> 5 blocks/CU),
// near-floor bank behavior for all pass strides.
__device__ inline int sw(int i) { return i ^ ((i >> 5) & 15); }

// e^{i*2pi*r} via HW trig. v_sin_f32/v_cos_f32 take REVOLUTIONS (ISA doc);
// all our twiddle args are exact dyadic fractions in (-1,1) -> no range
// reduction. Replaces libm sincosf (~30-40 VALU ops) with 2 trans ops.
__device__ inline float2 cexp_rev(float r) {
    return make_float2(__builtin_amdgcn_cosf(r), __builtin_amdgcn_sinf(r));
}

// w[p] = e^{i*2pi*r*p}, p=1..7: one hw sin/cos + squared chains.
__device__ inline void tw8r(float r, float2* w) {
    w[1] = cexp_rev(r);
    w[2] = cmul(w[1], w[1]);
    w[3] = cmul(w[2], w[1]);
    w[4] = cmul(w[2], w[2]);
    w[5] = cmul(w[3], w[2]);
    w[6] = cmul(w[3], w[3]);
    w[7] = cmul(w[4], w[3]);
}

// ---------------- radix-8 butterflies ----------------
// Forward DIF with output twiddles w (powers of e^{-2pi i j/M}).
__device__ inline void fwd8(float2* P, int base, int stride, const float2* w) {
    const float C = 0.70710678118654752f;
    float2 v[8];
    #pragma unroll
    for (int r = 0; r < 8; ++r) v[r] = P[sw(base + stride * r)];
    float2 y0 = cadd(v[0], v[4]), y1 = cadd(v[1], v[5]);
    float2 y2 = cadd(v[2], v[6]), y3 = cadd(v[3], v[7]);
    float2 t0 = csub(v[0], v[4]), t1 = csub(v[1], v[5]);
    float2 t2 = csub(v[2], v[6]), t3 = csub(v[3], v[7]);
    float2 z0 = t0;
    float2 z1 = make_float2(C * (t1.x + t1.y), C * (t1.y - t1.x));   // t1 * (C,-C)
    float2 z2 = make_float2(t2.y, -t2.x);                            // t2 * (0,-1)
    float2 z3 = make_float2(C * (t3.y - t3.x), -C * (t3.x + t3.y));  // t3 * (-C,-C)
    float2 a0 = cadd(y0, y2), a1 = cadd(y1, y3);
    float2 b0 = csub(y0, y2), tb = csub(y1, y3);
    float2 b1 = make_float2(tb.y, -tb.x);
    float2 c0 = cadd(z0, z2), c1 = cadd(z1, z3);
    float2 d0 = csub(z0, z2), td = csub(z1, z3);
    float2 d1 = make_float2(td.y, -td.x);
    float2 X0 = cadd(a0, a1), X4 = csub(a0, a1);
    float2 X2 = cadd(b0, b1), X6 = csub(b0, b1);
    float2 X1 = cadd(c0, c1), X5 = csub(c0, c1);
    float2 X3 = cadd(d0, d1), X7 = csub(d0, d1);
    P[sw(base)]              = X0;
    P[sw(base + stride)]     = cmul(X1, w[1]);
    P[sw(base + 2 * stride)] = cmul(X2, w[2]);
    P[sw(base + 3 * stride)] = cmul(X3, w[3]);
    P[sw(base + 4 * stride)] = cmul(X4, w[4]);
    P[sw(base + 5 * stride)] = cmul(X5, w[5]);
    P[sw(base + 6 * stride)] = cmul(X6, w[6]);
    P[sw(base + 7 * stride)] = cmul(X7, w[7]);
}

// Forward DIF, last pass (M=8, j=0): no twiddles, contiguous stride 1.
__device__ inline void fwd8nt(float2* P, int base) {
    const float C = 0.70710678118654752f;
    float2 v[8];
    #pragma unroll
    for (int r = 0; r < 8; ++r) v[r] = P[sw(base + r)];
    float2 y0 = cadd(v[0], v[4]), y1 = cadd(v[1], v[5]);
    float2 y2 = cadd(v[2], v[6]), y3 = cadd(v[3], v[7]);
    float2 t0 = csub(v[0], v[4]), t1 = csub(v[1], v[5]);
    float2 t2 = csub(v[2], v[6]), t3 = csub(v[3], v[7]);
    float2 z0 = t0;
    float2 z1 = make_float2(C * (t1.x + t1.y), C * (t1.y - t1.x));
    float2 z2 = make_float2(t2.y, -t2.x);
    float2 z3 = make_float2(C * (t3.y - t3.x), -C * (t3.x + t3.y));
    float2 a0 = cadd(y0, y2), a1 = cadd(y1, y3);
    float2 b0 = csub(y0, y2), tb = csub(y1, y3);
    float2 b1 = make_float2(tb.y, -tb.x);
    float2 c0 = cadd(z0, z2), c1 = cadd(z1, z3);
    float2 d0 = csub(z0, z2), td = csub(z1, z3);
    float2 d1 = make_float2(td.y, -td.x);
    P[sw(base)]     = cadd(a0, a1);
    P[sw(base + 4)] = csub(a0, a1);
    P[sw(base + 2)] = cadd(b0, b1);
    P[sw(base + 6)] = csub(b0, b1);
    P[sw(base + 1)] = cadd(c0, c1);
    P[sw(base + 5)] = csub(c0, c1);
    P[sw(base + 3)] = cadd(d0, d1);
    P[sw(base + 7)] = csub(d0, d1);
}

// Inverse DIT with input twiddles w (powers of e^{+2pi i j/M}).
__device__ inline void inv8(float2* P, int base, int stride, const float2* w) {
    const float C = 0.70710678118654752f;
    float2 v[8];
    #pragma unroll
    for (int p = 0; p < 8; ++p) v[p] = P[sw(base + stride * p)];
    #pragma unroll
    for (int p = 1; p < 8; ++p) v[p] = cmul(v[p], w[p]);
    float2 y0 = cadd(v[0], v[4]), y1 = cadd(v[1], v[5]);
    float2 y2 = cadd(v[2], v[6]), y3 = cadd(v[3], v[7]);
    float2 t0 = csub(v[0], v[4]), t1 = csub(v[1], v[5]);
    float2 t2 = csub(v[2], v[6]), t3 = csub(v[3], v[7]);
    float2 z0 = t0;
    float2 z1 = make_float2(C * (t1.x - t1.y), C * (t1.x + t1.y));   // t1 * (C, C)
    float2 z2 = make_float2(-t2.y, t2.x);                            // t2 * (0, 1)
    float2 z3 = make_float2(-C * (t3.x + t3.y), C * (t3.x - t3.y));  // t3 * (-C, C)
    float2 a0 = cadd(y0, y2), a1 = cadd(y1, y3);
    float2 b0 = csub(y0, y2), tb = csub(y1, y3);
    float2 b1 = make_float2(-tb.y, tb.x);
    float2 c0 = cadd(z0, z2), c1 = cadd(z1, z3);
    float2 d0 = csub(z0, z2), td = csub(z1, z3);
    float2 d1 = make_float2(-td.y, td.x);
    P[sw(base)]              = cadd(a0, a1);
    P[sw(base + 4 * stride)] = csub(a0, a1);
    P[sw(base + 2 * stride)] = cadd(b0, b1);
    P[sw(base + 6 * stride)] = csub(b0, b1);
    P[sw(base + stride)]     = cadd(c0, c1);
    P[sw(base + 5 * stride)] = csub(c0, c1);
    P[sw(base + 3 * stride)] = cadd(d0, d1);
    P[sw(base + 7 * stride)] = csub(d0, d1);
}

// Inverse DIT, first pass (M=8, j=0): no input twiddles.
__device__ inline void inv8nt(float2* P, int base) {
    const float C = 0.70710678118654752f;
    float2 v[8];
    #pragma unroll
    for (int p = 0; p < 8; ++p) v[p] = P[sw(base + p)];
    float2 y0 = cadd(v[0], v[4]), y1 = cadd(v[1], v[5]);
    float2 y2 = cadd(v[2], v[6]), y3 = cadd(v[3], v[7]);
    float2 t0 = csub(v[0], v[4]), t1 = csub(v[1], v[5]);
    float2 t2 = csub(v[2], v[6]), t3 = csub(v[3], v[7]);
    float2 z0 = t0;
    float2 z1 = make_float2(C * (t1.x - t1.y), C * (t1.x + t1.y));
    float2 z2 = make_float2(-t2.y, t2.x);
    float2 z3 = make_float2(-C * (t3.x + t3.y), C * (t3.x - t3.y));
    float2 a0 = cadd(y0, y2), a1 = cadd(y1, y3);
    float2 b0 = csub(y0, y2), tb = csub(y1, y3);
    float2 b1 = make_float2(-tb.y, tb.x);
    float2 c0 = cadd(z0, z2), c1 = cadd(z1, z3);
    float2 d0 = csub(z0, z2), td = csub(z1, z3);
    float2 d1 = make_float2(-td.y, td.x);
    P[sw(base)]     = cadd(a0, a1);
    P[sw(base + 4)] = csub(a0, a1);
    P[sw(base + 2)] = cadd(b0, b1);
    P[sw(base + 6)] = csub(b0, b1);
    P[sw(base + 1)] = cadd(c0, c1);
    P[sw(base + 5)] = csub(c0, c1);
    P[sw(base + 3)] = cadd(d0, d1);
    P[sw(base + 7)] = csub(d0, d1);
}

// ---------------- radix-4 block-wide passes (stride 512, M=2048) ----------------
__device__ inline void fwd4s(float2* P, int j) {
    float2 v0 = P[sw(j)], v1 = P[sw(j + 512)], v2 = P[sw(j + 1024)], v3 = P[sw(j + 1536)];
    float2 a0 = cadd(v0, v2), a1 = cadd(v1, v3);
    float2 b0 = csub(v0, v2), t = csub(v1, v3);
    float2 b1 = make_float2(t.y, -t.x);                 // t * (-i)
    float2 X0 = cadd(a0, a1), X2 = csub(a0, a1);
    float2 X1 = cadd(b0, b1), X3 = csub(b0, b1);
    float2 w1 = cexp_rev(-(float)j * (1.0f / 2048.0f));
    float2 w2 = cmul(w1, w1);
    float2 w3 = cmul(w2, w1);
    P[sw(j)]        = X0;
    P[sw(j + 512)]  = cmul(X1, w1);
    P[sw(j + 1024)] = cmul(X2, w2);
    P[sw(j + 1536)] = cmul(X3, w3);
}
__device__ inline void inv4s(float2* P, int j) {
    float2 v0 = P[sw(j)], v1 = P[sw(j + 512)], v2 = P[sw(j + 1024)], v3 = P[sw(j + 1536)];
    float2 w1 = cexp_rev((float)j * (1.0f / 2048.0f));
    float2 w2 = cmul(w1, w1);
    float2 w3 = cmul(w2, w1);
    v1 = cmul(v1, w1); v2 = cmul(v2, w2); v3 = cmul(v3, w3);
    float2 a0 = cadd(v0, v2), a1 = cadd(v1, v3);
    float2 b0 = csub(v0, v2), t = csub(v1, v3);
    float2 b1 = make_float2(-t.y, t.x);                 // t * (+i)
    P[sw(j)]        = cadd(a0, a1);
    P[sw(j + 1024)] = csub(a0, a1);
    P[sw(j + 512)]  = cadd(b0, b1);
    P[sw(j + 1536)] = csub(b0, b1);
}

// Storage slot of frequency k after DIF radices 4(512),8(64),8(8),8(1).
__device__ inline int slotOf(int k) {
    return ((k & 3) << 9) | (((k >> 2) & 7) << 6) | (((k >> 5) & 7) << 3) | ((k >> 8) & 7);
}

// Packed FFT correlation core. 2048 = 4 x 512: block-wide radix-4 pass, then
// wave-local 8x8x8 on contiguous 512-pt chunks (no barriers inside).
__device__ inline void fft_core(float2* A, float2* Bs, int tid) {
    int lane  = tid & 63;
    int chunk = (tid >> 6) << 9;    // 512 * wave
    float2 w[8];

    // ---- forward pass 1 (block-wide)
    fwd4s(A, tid);  fwd4s(A, tid + 256);
    fwd4s(Bs, tid); fwd4s(Bs, tid + 256);
    __syncthreads();

    // ---- forward passes 2-4 (wave-local on chunk)
    tw8r(-(float)lane * (1.0f / 512.0f), w);
    fwd8(A,  chunk + lane, 64, w);
    fwd8(Bs, chunk + lane, 64, w);
    {
        int base = chunk + ((lane >> 3) << 6) + (lane & 7);
        tw8r(-(float)(lane & 7) * (1.0f / 64.0f), w);
        fwd8(A,  base, 8, w);
        fwd8(Bs, base, 8, w);
    }
    fwd8nt(A,  chunk + (lane << 3));
    fwd8nt(Bs, chunk + (lane << 3));
    __syncthreads();

    // ---- pointwise in digit-reversed domain: Hermitian unpack of packed
    // real pair, C = Q*conj(K) per channel, repack W = C0 + i*C1.
    for (int f = tid; f <= 1024; f += 256) {
        int nf = (2048 - f) & 2047;
        int ia = sw(slotOf(f));
        int ib = sw(slotOf(nf));
        float2 z1 = A[ia],  z1n = A[ib];
        float2 z2 = Bs[ia], z2n = Bs[ib];
        float Qx = 0.5f * (z1.x + z1n.x), Qy = 0.5f * (z1.y - z1n.y);
        float Kx = 0.5f * (z1.y + z1n.y), Ky = 0.5f * (z1n.x - z1.x);
        float C1x = Qx * Kx + Qy * Ky;
        float C1y = Qy * Kx - Qx * Ky;
        float Px = 0.5f * (z2.x + z2n.x), Py = 0.5f * (z2.y - z2n.y);
        float Lx = 0.5f * (z2.y + z2n.y), Ly = 0.5f * (z2n.x - z2.x);
        float C2x = Px * Lx + Py * Ly;
        float C2y = Py * Lx - Px * Ly;
        A[ia] = make_float2(C1x - C2y, C1y + C2x);
        if (f != 0 && f != 1024)
            A[ib] = make_float2(C1x + C2y, C2x - C1y);
    }
    __syncthreads();

    // ---- inverse passes 1-3 (wave-local on chunk, A only)
    inv8nt(A, chunk + (lane << 3));
    {
        int base = chunk + ((lane >> 3) << 6) + (lane & 7);
        tw8r((float)(lane & 7) * (1.0f / 64.0f), w);
        inv8(A, base, 8, w);
    }
    tw8r((float)lane * (1.0f / 512.0f), w);
    inv8(A, chunk + lane, 64, w);
    __syncthreads();

    // ---- inverse pass 4 (block-wide)
    inv4s(A, tid); inv4s(A, tid + 256);
    __syncthreads();
}

// K1: read q,k strided directly from (B,L,E); XCD-aware swizzle (round-5 win:
// FETCH 765->66 MB) keeps the 8 blocks sharing each 64B line on one XCD's L2.
__global__ __launch_bounds__(256) void fft_corr_strided(const float* __restrict__ q,
                                                        const float* __restrict__ k,
                                                        float* __restrict__ corr,
                                                        int chStart) {
    __shared__ float2 A[LEN];
    __shared__ float2 Bs[LEN];
    int bid = blockIdx.x;
    int nwg = gridDim.x;
    int cp  = ((nwg & (NXCD - 1)) == 0) ? (bid & (NXCD - 1)) * (nwg >> 3) + (bid >> 3)
                                        : bid;   // bijective only when nwg%8==0
    int chLocal = cp * 2;
    int gch = chStart + chLocal;
    int b   = gch >> 9;           // / EDIM
    int e   = gch & (EDIM - 1);   // even (channels paired)
    int tid = threadIdx.x;
    const float* qr = q + (size_t)b * LEN * EDIM + e;
    const float* kr = k + (size_t)b * LEN * EDIM + e;
    #pragma unroll
    for (int j = 0; j < LEN / 256; ++j) {
        int t = tid + 256 * j;
        float2 qv = *(const float2*)(qr + (size_t)t * EDIM);
        float2 kv = *(const float2*)(kr + (size_t)t * EDIM);
        A[sw(t)]  = make_float2(qv.x, kv.x);
        Bs[sw(t)] = make_float2(qv.y, kv.y);
    }
    __syncthreads();
    fft_core(A, Bs, tid);
    const float inv = 1.0f / (float)LEN;
    float4* c0 = (float4*)(corr + (size_t)chLocal * LEN);
    float4* c1 = (float4*)(corr + (size_t)(chLocal + 1) * LEN);
    for (int t4 = tid; t4 < LEN / 4; t4 += 256) {
        int t = t4 * 4;
        float2 e0 = A[sw(t)], e1 = A[sw(t + 1)], e2 = A[sw(t + 2)], e3 = A[sw(t + 3)];
        c0[t4] = make_float4(e0.x * inv, e1.x * inv, e2.x * inv, e3.x * inv);
        c1[t4] = make_float4(e0.y * inv, e1.y * inv, e2.y * inv, e3.y * inv);
    }
}

// K2: per (b,h,l): top-7 over 64 channel-scores, softmax, gather-weighted sum.
// Round-7 change: manufacture memory-level parallelism. Phase 2 unrolls l by
// 4 (28 independent global loads in flight per macro-iteration; VGPR was 20 --
// the compiler kept almost nothing in flight across the 448 serial gathers).
// Phase 1 bumps the corr-load unroll to 16.
__global__ __launch_bounds__(256) void topk_agg(const float* __restrict__ corr,
                                                const float* __restrict__ values,
                                                float* __restrict__ out,
                                                int bhBase) {
    __shared__ float2 w_d[256][TOPK];   // (weight, bitcast delay) per local l
    int l0 = blockIdx.x * 256;
    int lh = blockIdx.y;            // local head index within chunk
    int bh = bhBase + lh;
    int b  = bh >> 3;
    int h  = bh & 7;
    int tid = threadIdx.x;

    const float* cb = corr + (size_t)lh * HD * LEN + l0 + tid;
    float wk[TOPK];
    int   dk[TOPK];
    #pragma unroll
    for (int t = 0; t < TOPK; ++t) { wk[t] = -INFINITY; dk[t] = 0; }
    #pragma unroll 16
    for (int c = 0; c < HD; ++c) {
        float nv = cb[(size_t)c * LEN];
        int   nd = c;
        #pragma unroll
        for (int t = 0; t < TOPK; ++t) {   // stable: strict > keeps low index first
            bool  m  = nv > wk[t];
            float tv = wk[t]; int td = dk[t];
            wk[t] = m ? nv : tv;
            dk[t] = m ? nd : td;
            nv    = m ? tv : nv;
            nd    = m ? td : nd;
        }
    }
    float mx = wk[0], sum = 0.f;
    float e[TOPK];
    #pragma unroll
    for (int t = 0; t < TOPK; ++t) { e[t] = expf(wk[t] - mx); sum += e[t]; }
    float invs = 1.f / sum;
    #pragma unroll
    for (int t = 0; t < TOPK; ++t)
        w_d[tid][t] = make_float2(e[t] * invs, __int_as_float(dk[t]));
    __syncthreads();

    int lane = tid & 63;
    int wave = tid >> 6;
    const float* vb = values + (size_t)b * LEN * EDIM + h * HD + lane;
    float*       ob = out    + (size_t)b * LEN * EDIM + h * HD + lane;
    for (int i0 = 0; i0 < 64; i0 += 4) {
        float acc0 = 0.f, acc1 = 0.f, acc2 = 0.f, acc3 = 0.f;
        int lpb = wave * 64 + i0;
        int lb  = l0 + lpb;
        #pragma unroll
        for (int t = 0; t < TOPK; ++t) {
            float2 wd0 = w_d[lpb + 0][t];
            float2 wd1 = w_d[lpb + 1][t];
            float2 wd2 = w_d[lpb + 2][t];
            float2 wd3 = w_d[lpb + 3][t];
            int i0x = (lb + 0 - __float_as_int(wd0.y)) & (LEN - 1);
            int i1x = (lb + 1 - __float_as_int(wd1.y)) & (LEN - 1);
            int i2x = (lb + 2 - __float_as_int(wd2.y)) & (LEN - 1);
            int i3x = (lb + 3 - __float_as_int(wd3.y)) & (LEN - 1);
            acc0 += wd0.x * vb[(size_t)i0x * EDIM];
            acc1 += wd1.x * vb[(size_t)i1x * EDIM];
            acc2 += wd2.x * vb[(size_t)i2x * EDIM];
            acc3 += wd3.x * vb[(size_t)i3x * EDIM];
        }
        ob[(size_t)(lb + 0) * EDIM] = acc0;
        ob[(size_t)(lb + 1) * EDIM] = acc1;
        ob[(size_t)(lb + 2) * EDIM] = acc2;
        ob[(size_t)(lb + 3) * EDIM] = acc3;
    }
}

extern "C" void kernel_launch(void* const* d_in, const int* in_sizes, int n_in,
                              void* d_out, int out_size, void* d_ws, size_t ws_size,
                              hipStream_t stream) {
    const float* q = (const float*)d_in[0];
    const float* k = (const float*)d_in[1];
    const float* v = (const float*)d_in[2];
    float* out = (float*)d_out;

    const size_t CORR_BYTES = (size_t)NB * EDIM * LEN * sizeof(float);  // 64 MB

    if (ws_size >= CORR_BYTES) {
        // Full pipeline, transpose-free: corr (64 MB) lives in ws.
        float* corr = (float*)d_ws;
        fft_corr_strided<<<dim3(NB * EDIM / 2), dim3(256), 0, stream>>>(q, k, corr, 0);
        topk_agg<<<dim3(LEN / 256, NB * NH), dim3(256), 0, stream>>>(corr, v, out, 0);
    } else {
        // Chunk by heads; corr chunk lives in ws (512 KB per head).
        const size_t HEAD_BYTES = (size_t)HD * LEN * sizeof(float);
        int headsPer = (int)(ws_size / HEAD_BYTES);
        if (headsPer < 1) headsPer = 1;
        if (headsPer > NB * NH) headsPer = NB * NH;
        float* corr = (float*)d_ws;
        for (int hs = 0; hs < NB * NH; hs += headsPer) {
            int hc = NB * NH - hs < headsPer ? NB * NH - hs : headsPer;
            fft_corr_strided<<<dim3(hc * HD / 2), dim3(256), 0, stream>>>(q, k, corr, hs * HD);
            topk_agg<<<dim3(LEN / 256, hc), dim3(256), 0, stream>>>(corr, v, out, hs);
        }
    }
}

// Round 8
// 312.784 us; speedup vs baseline: 1.0152x; 1.0152x over previous
//
#include <hip/hip_runtime.h>
#include <math.h>

#define LEN   2048
#define EDIM  512
#define NB    16
#define NH    8
#define HD    64
#define TOPK  7
#define NXCD  8
#define LBLK  64     // l's per topk block (single-wave blocks)

__device__ inline float2 cmul(float2 a, float2 b) {
    return make_float2(a.x * b.x - a.y * b.y, a.x * b.y + a.y * b.x);
}
__device__ inline float2 cadd(float2 a, float2 b) { return make_float2(a.x + b.x, a.y + b.y); }
__device__ inline float2 csub(float2 a, float2 b) { return make_float2(a.x - b.x, a.y - b.y); }
// XOR swizzle: arrays stay exactly 2048 float2 (A+Bs = 32 KB -> 5 blocks/CU),
// near-floor bank behavior for all pass strides.
__device__ inline int sw(int i) { return i ^ ((i >> 5) & 15); }

// e^{i*2pi*r} via HW trig (v_sin/cos take revolutions; dyadic args -> exact).
__device__ inline float2 cexp_rev(float r) {
    return make_float2(__builtin_amdgcn_cosf(r), __builtin_amdgcn_sinf(r));
}

// w[p] = e^{i*2pi*r*p}, p=1..7: one hw sin/cos + squared chains.
__device__ inline void tw8r(float r, float2* w) {
    w[1] = cexp_rev(r);
    w[2] = cmul(w[1], w[1]);
    w[3] = cmul(w[2], w[1]);
    w[4] = cmul(w[2], w[2]);
    w[5] = cmul(w[3], w[2]);
    w[6] = cmul(w[3], w[3]);
    w[7] = cmul(w[4], w[3]);
}

// ---------------- radix-8 butterflies ----------------
__device__ inline void fwd8(float2* P, int base, int stride, const float2* w) {
    const float C = 0.70710678118654752f;
    float2 v[8];
    #pragma unroll
    for (int r = 0; r < 8; ++r) v[r] = P[sw(base + stride * r)];
    float2 y0 = cadd(v[0], v[4]), y1 = cadd(v[1], v[5]);
    float2 y2 = cadd(v[2], v[6]), y3 = cadd(v[3], v[7]);
    float2 t0 = csub(v[0], v[4]), t1 = csub(v[1], v[5]);
    float2 t2 = csub(v[2], v[6]), t3 = csub(v[3], v[7]);
    float2 z0 = t0;
    float2 z1 = make_float2(C * (t1.x + t1.y), C * (t1.y - t1.x));   // t1 * (C,-C)
    float2 z2 = make_float2(t2.y, -t2.x);                            // t2 * (0,-1)
    float2 z3 = make_float2(C * (t3.y - t3.x), -C * (t3.x + t3.y));  // t3 * (-C,-C)
    float2 a0 = cadd(y0, y2), a1 = cadd(y1, y3);
    float2 b0 = csub(y0, y2), tb = csub(y1, y3);
    float2 b1 = make_float2(tb.y, -tb.x);
    float2 c0 = cadd(z0, z2), c1 = cadd(z1, z3);
    float2 d0 = csub(z0, z2), td = csub(z1, z3);
    float2 d1 = make_float2(td.y, -td.x);
    float2 X0 = cadd(a0, a1), X4 = csub(a0, a1);
    float2 X2 = cadd(b0, b1), X6 = csub(b0, b1);
    float2 X1 = cadd(c0, c1), X5 = csub(c0, c1);
    float2 X3 = cadd(d0, d1), X7 = csub(d0, d1);
    P[sw(base)]              = X0;
    P[sw(base + stride)]     = cmul(X1, w[1]);
    P[sw(base + 2 * stride)] = cmul(X2, w[2]);
    P[sw(base + 3 * stride)] = cmul(X3, w[3]);
    P[sw(base + 4 * stride)] = cmul(X4, w[4]);
    P[sw(base + 5 * stride)] = cmul(X5, w[5]);
    P[sw(base + 6 * stride)] = cmul(X6, w[6]);
    P[sw(base + 7 * stride)] = cmul(X7, w[7]);
}

__device__ inline void fwd8nt(float2* P, int base) {
    const float C = 0.70710678118654752f;
    float2 v[8];
    #pragma unroll
    for (int r = 0; r < 8; ++r) v[r] = P[sw(base + r)];
    float2 y0 = cadd(v[0], v[4]), y1 = cadd(v[1], v[5]);
    float2 y2 = cadd(v[2], v[6]), y3 = cadd(v[3], v[7]);
    float2 t0 = csub(v[0], v[4]), t1 = csub(v[1], v[5]);
    float2 t2 = csub(v[2], v[6]), t3 = csub(v[3], v[7]);
    float2 z0 = t0;
    float2 z1 = make_float2(C * (t1.x + t1.y), C * (t1.y - t1.x));
    float2 z2 = make_float2(t2.y, -t2.x);
    float2 z3 = make_float2(C * (t3.y - t3.x), -C * (t3.x + t3.y));
    float2 a0 = cadd(y0, y2), a1 = cadd(y1, y3);
    float2 b0 = csub(y0, y2), tb = csub(y1, y3);
    float2 b1 = make_float2(tb.y, -tb.x);
    float2 c0 = cadd(z0, z2), c1 = cadd(z1, z3);
    float2 d0 = csub(z0, z2), td = csub(z1, z3);
    float2 d1 = make_float2(td.y, -td.x);
    P[sw(base)]     = cadd(a0, a1);
    P[sw(base + 4)] = csub(a0, a1);
    P[sw(base + 2)] = cadd(b0, b1);
    P[sw(base + 6)] = csub(b0, b1);
    P[sw(base + 1)] = cadd(c0, c1);
    P[sw(base + 5)] = csub(c0, c1);
    P[sw(base + 3)] = cadd(d0, d1);
    P[sw(base + 7)] = csub(d0, d1);
}

__device__ inline void inv8(float2* P, int base, int stride, const float2* w) {
    const float C = 0.70710678118654752f;
    float2 v[8];
    #pragma unroll
    for (int p = 0; p < 8; ++p) v[p] = P[sw(base + stride * p)];
    #pragma unroll
    for (int p = 1; p < 8; ++p) v[p] = cmul(v[p], w[p]);
    float2 y0 = cadd(v[0], v[4]), y1 = cadd(v[1], v[5]);
    float2 y2 = cadd(v[2], v[6]), y3 = cadd(v[3], v[7]);
    float2 t0 = csub(v[0], v[4]), t1 = csub(v[1], v[5]);
    float2 t2 = csub(v[2], v[6]), t3 = csub(v[3], v[7]);
    float2 z0 = t0;
    float2 z1 = make_float2(C * (t1.x - t1.y), C * (t1.x + t1.y));   // t1 * (C, C)
    float2 z2 = make_float2(-t2.y, t2.x);                            // t2 * (0, 1)
    float2 z3 = make_float2(-C * (t3.x + t3.y), C * (t3.x - t3.y));  // t3 * (-C, C)
    float2 a0 = cadd(y0, y2), a1 = cadd(y1, y3);
    float2 b0 = csub(y0, y2), tb = csub(y1, y3);
    float2 b1 = make_float2(-tb.y, tb.x);
    float2 c0 = cadd(z0, z2), c1 = cadd(z1, z3);
    float2 d0 = csub(z0, z2), td = csub(z1, z3);
    float2 d1 = make_float2(-td.y, td.x);
    P[sw(base)]              = cadd(a0, a1);
    P[sw(base + 4 * stride)] = csub(a0, a1);
    P[sw(base + 2 * stride)] = cadd(b0, b1);
    P[sw(base + 6 * stride)] = csub(b0, b1);
    P[sw(base + stride)]     = cadd(c0, c1);
    P[sw(base + 5 * stride)] = csub(c0, c1);
    P[sw(base + 3 * stride)] = cadd(d0, d1);
    P[sw(base + 7 * stride)] = csub(d0, d1);
}

__device__ inline void inv8nt(float2* P, int base) {
    const float C = 0.70710678118654752f;
    float2 v[8];
    #pragma unroll
    for (int p = 0; p < 8; ++p) v[p] = P[sw(base + p)];
    float2 y0 = cadd(v[0], v[4]), y1 = cadd(v[1], v[5]);
    float2 y2 = cadd(v[2], v[6]), y3 = cadd(v[3], v[7]);
    float2 t0 = csub(v[0], v[4]), t1 = csub(v[1], v[5]);
    float2 t2 = csub(v[2], v[6]), t3 = csub(v[3], v[7]);
    float2 z0 = t0;
    float2 z1 = make_float2(C * (t1.x - t1.y), C * (t1.x + t1.y));
    float2 z2 = make_float2(-t2.y, t2.x);
    float2 z3 = make_float2(-C * (t3.x + t3.y), C * (t3.x - t3.y));
    float2 a0 = cadd(y0, y2), a1 = cadd(y1, y3);
    float2 b0 = csub(y0, y2), tb = csub(y1, y3);
    float2 b1 = make_float2(-tb.y, tb.x);
    float2 c0 = cadd(z0, z2), c1 = cadd(z1, z3);
    float2 d0 = csub(z0, z2), td = csub(z1, z3);
    float2 d1 = make_float2(-td.y, td.x);
    P[sw(base)]     = cadd(a0, a1);
    P[sw(base + 4)] = csub(a0, a1);
    P[sw(base + 2)] = cadd(b0, b1);
    P[sw(base + 6)] = csub(b0, b1);
    P[sw(base + 1)] = cadd(c0, c1);
    P[sw(base + 5)] = csub(c0, c1);
    P[sw(base + 3)] = cadd(d0, d1);
    P[sw(base + 7)] = csub(d0, d1);
}

// ---------------- radix-4 block-wide passes (stride 512, M=2048) ----------------
__device__ inline void fwd4s(float2* P, int j) {
    float2 v0 = P[sw(j)], v1 = P[sw(j + 512)], v2 = P[sw(j + 1024)], v3 = P[sw(j + 1536)];
    float2 a0 = cadd(v0, v2), a1 = cadd(v1, v3);
    float2 b0 = csub(v0, v2), t = csub(v1, v3);
    float2 b1 = make_float2(t.y, -t.x);                 // t * (-i)
    float2 X0 = cadd(a0, a1), X2 = csub(a0, a1);
    float2 X1 = cadd(b0, b1), X3 = csub(b0, b1);
    float2 w1 = cexp_rev(-(float)j * (1.0f / 2048.0f));
    float2 w2 = cmul(w1, w1);
    float2 w3 = cmul(w2, w1);
    P[sw(j)]        = X0;
    P[sw(j + 512)]  = cmul(X1, w1);
    P[sw(j + 1024)] = cmul(X2, w2);
    P[sw(j + 1536)] = cmul(X3, w3);
}
__device__ inline void inv4s(float2* P, int j) {
    float2 v0 = P[sw(j)], v1 = P[sw(j + 512)], v2 = P[sw(j + 1024)], v3 = P[sw(j + 1536)];
    float2 w1 = cexp_rev((float)j * (1.0f / 2048.0f));
    float2 w2 = cmul(w1, w1);
    float2 w3 = cmul(w2, w1);
    v1 = cmul(v1, w1); v2 = cmul(v2, w2); v3 = cmul(v3, w3);
    float2 a0 = cadd(v0, v2), a1 = cadd(v1, v3);
    float2 b0 = csub(v0, v2), t = csub(v1, v3);
    float2 b1 = make_float2(-t.y, t.x);                 // t * (+i)
    P[sw(j)]        = cadd(a0, a1);
    P[sw(j + 1024)] = csub(a0, a1);
    P[sw(j + 512)]  = cadd(b0, b1);
    P[sw(j + 1536)] = csub(b0, b1);
}

// Storage slot of frequency k after DIF radices 4(512),8(64),8(8),8(1).
__device__ inline int slotOf(int k) {
    return ((k & 3) << 9) | (((k >> 2) & 7) << 6) | (((k >> 5) & 7) << 3) | ((k >> 8) & 7);
}

// Packed FFT correlation core. 2048 = 4 x 512: block-wide radix-4 pass, then
// wave-local 8x8x8 on contiguous 512-pt chunks (no barriers inside).
__device__ inline void fft_core(float2* A, float2* Bs, int tid) {
    int lane  = tid & 63;
    int chunk = (tid >> 6) << 9;    // 512 * wave
    float2 w[8];

    fwd4s(A, tid);  fwd4s(A, tid + 256);
    fwd4s(Bs, tid); fwd4s(Bs, tid + 256);
    __syncthreads();

    tw8r(-(float)lane * (1.0f / 512.0f), w);
    fwd8(A,  chunk + lane, 64, w);
    fwd8(Bs, chunk + lane, 64, w);
    {
        int base = chunk + ((lane >> 3) << 6) + (lane & 7);
        tw8r(-(float)(lane & 7) * (1.0f / 64.0f), w);
        fwd8(A,  base, 8, w);
        fwd8(Bs, base, 8, w);
    }
    fwd8nt(A,  chunk + (lane << 3));
    fwd8nt(Bs, chunk + (lane << 3));
    __syncthreads();

    // Pointwise in digit-reversed domain: Hermitian unpack of packed real
    // pair, C = Q*conj(K) per channel, repack W = C0 + i*C1.
    for (int f = tid; f <= 1024; f += 256) {
        int nf = (2048 - f) & 2047;
        int ia = sw(slotOf(f));
        int ib = sw(slotOf(nf));
        float2 z1 = A[ia],  z1n = A[ib];
        float2 z2 = Bs[ia], z2n = Bs[ib];
        float Qx = 0.5f * (z1.x + z1n.x), Qy = 0.5f * (z1.y - z1n.y);
        float Kx = 0.5f * (z1.y + z1n.y), Ky = 0.5f * (z1n.x - z1.x);
        float C1x = Qx * Kx + Qy * Ky;
        float C1y = Qy * Kx - Qx * Ky;
        float Px = 0.5f * (z2.x + z2n.x), Py = 0.5f * (z2.y - z2n.y);
        float Lx = 0.5f * (z2.y + z2n.y), Ly = 0.5f * (z2n.x - z2.x);
        float C2x = Px * Lx + Py * Ly;
        float C2y = Py * Lx - Px * Ly;
        A[ia] = make_float2(C1x - C2y, C1y + C2x);
        if (f != 0 && f != 1024)
            A[ib] = make_float2(C1x + C2y, C2x - C1y);
    }
    __syncthreads();

    inv8nt(A, chunk + (lane << 3));
    {
        int base = chunk + ((lane >> 3) << 6) + (lane & 7);
        tw8r((float)(lane & 7) * (1.0f / 64.0f), w);
        inv8(A, base, 8, w);
    }
    tw8r((float)lane * (1.0f / 512.0f), w);
    inv8(A, chunk + lane, 64, w);
    __syncthreads();

    inv4s(A, tid); inv4s(A, tid + 256);
    __syncthreads();
}

// K1: read q,k strided directly from (B,L,E); XCD-aware swizzle (round-5 win:
// FETCH 765->66 MB) keeps the 8 blocks sharing each 64B line on one XCD's L2.
// UNCHANGED this round (clean attribution for the topk restructure).
__global__ __launch_bounds__(256) void fft_corr_strided(const float* __restrict__ q,
                                                        const float* __restrict__ k,
                                                        float* __restrict__ corr,
                                                        int chStart) {
    __shared__ float2 A[LEN];
    __shared__ float2 Bs[LEN];
    int bid = blockIdx.x;
    int nwg = gridDim.x;
    int cp  = ((nwg & (NXCD - 1)) == 0) ? (bid & (NXCD - 1)) * (nwg >> 3) + (bid >> 3)
                                        : bid;   // bijective only when nwg%8==0
    int chLocal = cp * 2;
    int gch = chStart + chLocal;
    int b   = gch >> 9;           // / EDIM
    int e   = gch & (EDIM - 1);   // even (channels paired)
    int tid = threadIdx.x;
    const float* qr = q + (size_t)b * LEN * EDIM + e;
    const float* kr = k + (size_t)b * LEN * EDIM + e;
    #pragma unroll
    for (int j = 0; j < LEN / 256; ++j) {
        int t = tid + 256 * j;
        float2 qv = *(const float2*)(qr + (size_t)t * EDIM);
        float2 kv = *(const float2*)(kr + (size_t)t * EDIM);
        A[sw(t)]  = make_float2(qv.x, kv.x);
        Bs[sw(t)] = make_float2(qv.y, kv.y);
    }
    __syncthreads();
    fft_core(A, Bs, tid);
    const float inv = 1.0f / (float)LEN;
    float4* c0 = (float4*)(corr + (size_t)chLocal * LEN);
    float4* c1 = (float4*)(corr + (size_t)(chLocal + 1) * LEN);
    for (int t4 = tid; t4 < LEN / 4; t4 += 256) {
        int t = t4 * 4;
        float2 e0 = A[sw(t)], e1 = A[sw(t + 1)], e2 = A[sw(t + 2)], e3 = A[sw(t + 3)];
        c0[t4] = make_float4(e0.x * inv, e1.x * inv, e2.x * inv, e3.x * inv);
        c1[t4] = make_float4(e0.y * inv, e1.y * inv, e2.y * inv, e3.y * inv);
    }
}

// K2: per (b,h,l): top-7 over 64 channel-scores, softmax, gather-weighted sum.
// ROUND-8 RESTRUCTURE: single-wave blocks. Old shape (1024 blocks of 4 waves
// = only 4 blocks/CU, block-wide barrier between VALU-bound phase 1 and
// VMEM-latency-bound phase 2) phase-aligned all resident waves, so the pipes
// never overlapped. Now: 64-thread blocks, LBLK=64, grid 32x128 = 4096 blocks
// -> 16+ blocks/CU (LDS 3.6 KB, VGPR ~48), waves independent and staggered:
// one wave's gathers overlap another's insertion network.
__global__ __launch_bounds__(64) void topk_agg(const float* __restrict__ corr,
                                               const float* __restrict__ values,
                                               float* __restrict__ out,
                                               int bhBase) {
    __shared__ float2 w_d[LBLK][TOPK];   // (weight, bitcast delay) per local l
    int l0 = blockIdx.x * LBLK;
    int lh = blockIdx.y;            // local head index within chunk
    int bh = bhBase + lh;
    int b  = bh >> 3;
    int h  = bh & 7;
    int tid = threadIdx.x;          // 0..63; = l-offset in phase 1, = channel in phase 2

    // ---- phase 1: per-thread top-7 over the 64 channels of row l = l0+tid
    const float* cb = corr + (size_t)lh * HD * LEN + l0 + tid;
    float wk[TOPK];
    int   dk[TOPK];
    #pragma unroll
    for (int t = 0; t < TOPK; ++t) { wk[t] = -INFINITY; dk[t] = 0; }
    #pragma unroll 16
    for (int c = 0; c < HD; ++c) {
        float nv = cb[(size_t)c * LEN];
        int   nd = c;
        #pragma unroll
        for (int t = 0; t < TOPK; ++t) {   // stable: strict > keeps low index first
            bool  m  = nv > wk[t];
            float tv = wk[t]; int td = dk[t];
            wk[t] = m ? nv : tv;
            dk[t] = m ? nd : td;
            nv    = m ? tv : nv;
            nd    = m ? td : nd;
        }
    }
    float mx = wk[0], sum = 0.f;
    float e[TOPK];
    #pragma unroll
    for (int t = 0; t < TOPK; ++t) { e[t] = expf(wk[t] - mx); sum += e[t]; }
    float invs = 1.f / sum;
    #pragma unroll
    for (int t = 0; t < TOPK; ++t)
        w_d[tid][t] = make_float2(e[t] * invs, __int_as_float(dk[t]));
    __syncthreads();   // single wave: near-free

    // ---- phase 2: gather. lane (=tid) = channel; this wave covers all 64 l.
    const float* vb = values + (size_t)b * LEN * EDIM + h * HD + tid;
    float*       ob = out    + (size_t)b * LEN * EDIM + h * HD + tid;
    for (int i0 = 0; i0 < LBLK; i0 += 4) {
        float acc0 = 0.f, acc1 = 0.f, acc2 = 0.f, acc3 = 0.f;
        int lb = l0 + i0;
        #pragma unroll
        for (int t = 0; t < TOPK; ++t) {
            float2 wd0 = w_d[i0 + 0][t];
            float2 wd1 = w_d[i0 + 1][t];
            float2 wd2 = w_d[i0 + 2][t];
            float2 wd3 = w_d[i0 + 3][t];
            int i0x = (lb + 0 - __float_as_int(wd0.y)) & (LEN - 1);
            int i1x = (lb + 1 - __float_as_int(wd1.y)) & (LEN - 1);
            int i2x = (lb + 2 - __float_as_int(wd2.y)) & (LEN - 1);
            int i3x = (lb + 3 - __float_as_int(wd3.y)) & (LEN - 1);
            acc0 += wd0.x * vb[(size_t)i0x * EDIM];
            acc1 += wd1.x * vb[(size_t)i1x * EDIM];
            acc2 += wd2.x * vb[(size_t)i2x * EDIM];
            acc3 += wd3.x * vb[(size_t)i3x * EDIM];
        }
        ob[(size_t)(lb + 0) * EDIM] = acc0;
        ob[(size_t)(lb + 1) * EDIM] = acc1;
        ob[(size_t)(lb + 2) * EDIM] = acc2;
        ob[(size_t)(lb + 3) * EDIM] = acc3;
    }
}

extern "C" void kernel_launch(void* const* d_in, const int* in_sizes, int n_in,
                              void* d_out, int out_size, void* d_ws, size_t ws_size,
                              hipStream_t stream) {
    const float* q = (const float*)d_in[0];
    const float* k = (const float*)d_in[1];
    const float* v = (const float*)d_in[2];
    float* out = (float*)d_out;

    const size_t CORR_BYTES = (size_t)NB * EDIM * LEN * sizeof(float);  // 64 MB

    if (ws_size >= CORR_BYTES) {
        // Full pipeline, transpose-free: corr (64 MB) lives in ws.
        float* corr = (float*)d_ws;
        fft_corr_strided<<<dim3(NB * EDIM / 2), dim3(256), 0, stream>>>(q, k, corr, 0);
        topk_agg<<<dim3(LEN / LBLK, NB * NH), dim3(LBLK), 0, stream>>>(corr, v, out, 0);
    } else {
        // Chunk by heads; corr chunk lives in ws (512 KB per head).
        const size_t HEAD_BYTES = (size_t)HD * LEN * sizeof(float);
        int headsPer = (int)(ws_size / HEAD_BYTES);
        if (headsPer < 1) headsPer = 1;
        if (headsPer > NB * NH) headsPer = NB * NH;
        float* corr = (float*)d_ws;
        for (int hs = 0; hs < NB * NH; hs += headsPer) {
            int hc = NB * NH - hs < headsPer ? NB * NH - hs : headsPer;
            fft_corr_strided<<<dim3(hc * HD / 2), dim3(256), 0, stream>>>(q, k, corr, hs * HD);
            topk_agg<<<dim3(LEN / LBLK, hc), dim3(LBLK), 0, stream>>>(corr, v, out, hs);
        }
    }
}